// Round 9
// baseline (1229.142 us; speedup 1.0000x reference)
//
#include <hip/hip_runtime.h>
#include <math.h>

// ---------------------------------------------------------------------------
// CommunityTrustGNN: 2-layer GraphSAGE (mean agg) + trust MLP head
// N=100000 nodes, E=1600000 edges, dims 64 -> 64 -> 32 -> (16 -> 1)
//
// Round 9: EDGE-PARALLEL aggregation via per-bucket LDS accumulators.
//  * Buckets shrink to 128 dst-nodes; a block holds the full f32 accumulator
//    in LDS (128x64 ~ 34KB). Edges processed half-wave-parallel with
//    ds_add_f32 -> no per-node serial walks (round 8 showed those are the
//    latency wall), no adj/nodeOff/k_csr at all.
//  * k_a1 = edge-par agg1 + (gemm2 from LDS h1). k_a2 = edge-par agg2 +
//    trust head. Degree via LDS histogram in the same pass.
//  * gemm1 LDS tile now row-major stride-68, float4 k-strips: kills the
//    4.85M bank conflicts from the round-7/8 transpose store.
// ---------------------------------------------------------------------------

#define NBUCK   782      // ceil(100000/128)
#define BCAP    2816     // bucket capacity (mean 2046, +17 sigma)
#define BKCHUNK 4096     // edges per bucket-chunk block in M1

// bf16 helpers (round-to-nearest-even pack, exact unpack)
__device__ inline unsigned short f2bf(float x) {
    unsigned u = __float_as_uint(x);
    unsigned r = u + 0x7fffu + ((u >> 16) & 1u);
    return (unsigned short)(r >> 16);
}
__device__ inline unsigned pack2(float a, float b) {
    return (unsigned)f2bf(a) | ((unsigned)f2bf(b) << 16);
}
__device__ inline float bflo(unsigned u) { return __uint_as_float(u << 16); }
__device__ inline float bfhi(unsigned u) { return __uint_as_float(u & 0xffff0000u); }

// --- M1: interleaved gemm1 tiles + bucket-scatter chunks --------------------
// blockIdx%5==4 -> bucket chunk (blockIdx/5); else gemm tile 4*(b/5)+(b%5).
// gemm1: u(bf16) = x@Wl1 ; v(f32) = x@Wr1 + b1  (two 64-col passes)
// bucket: edges -> packed (src | local_dst<<17), grouped by dst>>7
__global__ __launch_bounds__(256) void k_m1(
    const float* __restrict__ x,
    const float* __restrict__ Wl1, const float* __restrict__ Wr1,
    const float* __restrict__ b1,
    unsigned* __restrict__ u16b, float* __restrict__ v,
    const int* __restrict__ src, const int* __restrict__ dst,
    int* __restrict__ gcnt, unsigned* __restrict__ pairs,
    int N, int E, int GB, int BKB)
{
    __shared__ __align__(16) char smem[33792]; // sX 17408 + sW 16384 | hist 3128
    int tid = threadIdx.x;
    int g = blockIdx.x / 5, r5 = blockIdx.x % 5;

    if (r5 == 4) {
        // ---------------- bucket-scatter path ----------------
        if (g >= BKB) return;
        int* hist = (int*)smem;               // NBUCK ints
        int e0 = g * BKCHUNK;
        int e1 = min(e0 + BKCHUNK, E);

        for (int i = tid; i < NBUCK; i += 256) hist[i] = 0;
        __syncthreads();
        for (int e = e0 + tid; e < e1; e += 256)
            atomicAdd(&hist[((unsigned)dst[e]) >> 7], 1);
        __syncthreads();
        for (int i = tid; i < NBUCK; i += 256)
            if (hist[i] > 0)
                hist[i] = i * BCAP + atomicAdd(&gcnt[i], hist[i]);
        __syncthreads();
        for (int e = e0 + tid; e < e1; e += 256) {
            int t = dst[e];
            int b = ((unsigned)t) >> 7;
            int pos = atomicAdd(&hist[b], 1);
            pairs[pos] = (unsigned)src[e] | ((unsigned)(t & 127) << 17);
        }
        return;
    }

    // ---------------- gemm1 path ----------------
    int tile = 4 * g + r5;
    if (tile >= GB) return;
    float* sX = (float*)smem;             // 64 x stride68, row-major [m][k]
    float* sW = (float*)(smem + 17408);   // 64*64 [k][n], per pass
    int nblk = tile * 64;

    for (int i = tid * 4; i < 64 * 64; i += 1024) {
        int r = i >> 6, c = i & 63;
        int node = nblk + r;
        float4 xv = (node < N) ? *(const float4*)&x[(size_t)node * 64 + c]
                               : make_float4(0.f, 0.f, 0.f, 0.f);
        *(float4*)&sX[r * 68 + c] = xv;   // conflict-free b128 store
    }

    int mg = tid >> 4, ng = tid & 15;
    int m0 = mg * 4, n0 = ng * 4;

    #pragma unroll
    for (int pass = 0; pass < 2; ++pass) {
        const float* W = pass ? Wr1 : Wl1;
        if (pass) __syncthreads();
        for (int i = tid * 4; i < 64 * 64; i += 1024)
            *(float4*)&sW[i] = *(const float4*)&W[i];
        __syncthreads();

        float acc[4][4];
        #pragma unroll
        for (int mi = 0; mi < 4; ++mi)
            #pragma unroll
            for (int ni = 0; ni < 4; ++ni) acc[mi][ni] = 0.0f;

        #pragma unroll
        for (int k0 = 0; k0 < 64; k0 += 4) {
            float4 a[4], w[4];
            #pragma unroll
            for (int mi = 0; mi < 4; ++mi)
                a[mi] = *(float4*)&sX[(m0 + mi) * 68 + k0];
            #pragma unroll
            for (int kk = 0; kk < 4; ++kk)
                w[kk] = *(float4*)&sW[(k0 + kk) * 64 + n0];
            #pragma unroll
            for (int mi = 0; mi < 4; ++mi) {
                float am[4] = {a[mi].x, a[mi].y, a[mi].z, a[mi].w};
                #pragma unroll
                for (int kk = 0; kk < 4; ++kk) {
                    acc[mi][0] = fmaf(am[kk], w[kk].x, acc[mi][0]);
                    acc[mi][1] = fmaf(am[kk], w[kk].y, acc[mi][1]);
                    acc[mi][2] = fmaf(am[kk], w[kk].z, acc[mi][2]);
                    acc[mi][3] = fmaf(am[kk], w[kk].w, acc[mi][3]);
                }
            }
        }

        if (pass == 0) {
            #pragma unroll
            for (int mi = 0; mi < 4; ++mi) {
                int node = nblk + m0 + mi;
                if (node >= N) continue;
                uint2 pk;
                pk.x = pack2(acc[mi][0], acc[mi][1]);
                pk.y = pack2(acc[mi][2], acc[mi][3]);
                *(uint2*)&u16b[(size_t)node * 32 + (n0 >> 1)] = pk;
            }
        } else {
            float4 b0 = *(const float4*)&b1[n0];
            #pragma unroll
            for (int mi = 0; mi < 4; ++mi) {
                int node = nblk + m0 + mi;
                if (node >= N) continue;
                *(float4*)&v[(size_t)node * 64 + n0] =
                    make_float4(acc[mi][0]+b0.x, acc[mi][1]+b0.y,
                                acc[mi][2]+b0.z, acc[mi][3]+b0.w);
            }
        }
    }
}

// --- A1: edge-parallel agg1 + gemm2, one block per 128-node bucket ----------
// Phase E: half-wave per edge: acc[local_dst] += u16b[src] (ds_add_f32).
// Phase H: h1 = relu(acc*invd + v) in LDS. Phase B: P(bf16)=h1@Wl2, Q=h1@Wr2+b2.
__global__ __launch_bounds__(512) void k_a1(
    const unsigned* __restrict__ pairs, const int* __restrict__ gcnt,
    const unsigned* __restrict__ u16b, const float* __restrict__ v,
    const float* __restrict__ Wl2, const float* __restrict__ Wr2,
    const float* __restrict__ b2,
    unsigned* __restrict__ P16b, float* __restrict__ Qout,
    float* __restrict__ invdArr, int N)
{
    __shared__ float accF[128 * 68];   // 34816B, [node][dim] stride 68
    __shared__ float sW[64 * 64];      // 16384B: 0..31 Wl2 | 32..63 Wr2
    __shared__ int   sdeg[128];
    __shared__ float sInv[128];
    int tid = threadIdx.x;
    int b = blockIdx.x;
    int nodeBase = b * 128;

    for (int i = tid * 4; i < 128 * 68; i += 2048)
        *(float4*)&accF[i] = make_float4(0.f, 0.f, 0.f, 0.f);
    for (int i = tid * 4; i < 64 * 64; i += 2048) {
        int k = i >> 6, n = i & 63;
        const float* Wsrc = (n < 32) ? (Wl2 + k * 32 + n) : (Wr2 + k * 32 + (n - 32));
        *(float4*)&sW[k * 64 + n] = *(const float4*)Wsrc;
    }
    if (tid < 128) sdeg[tid] = 0;
    __syncthreads();

    // ---- Phase E: edge-parallel accumulate ----
    int count = min(gcnt[b], BCAP);
    const unsigned* pp = pairs + (size_t)b * BCAP;
    int hw = tid >> 5, lane = tid & 31;

    int j = hw;
    for (; j + 48 < count; j += 64) {
        unsigned e0 = pp[j], e1 = pp[j + 16], e2 = pp[j + 32], e3 = pp[j + 48];
        unsigned w0 = u16b[(size_t)(e0 & 0x1FFFFu) * 32 + lane];
        unsigned w1 = u16b[(size_t)(e1 & 0x1FFFFu) * 32 + lane];
        unsigned w2 = u16b[(size_t)(e2 & 0x1FFFFu) * 32 + lane];
        unsigned w3 = u16b[(size_t)(e3 & 0x1FFFFu) * 32 + lane];
        int d0 = (e0 >> 17) & 127, d1 = (e1 >> 17) & 127;
        int d2 = (e2 >> 17) & 127, d3 = (e3 >> 17) & 127;
        atomicAdd(&accF[d0 * 68 + 2 * lane],     bflo(w0));
        atomicAdd(&accF[d0 * 68 + 2 * lane + 1], bfhi(w0));
        atomicAdd(&accF[d1 * 68 + 2 * lane],     bflo(w1));
        atomicAdd(&accF[d1 * 68 + 2 * lane + 1], bfhi(w1));
        atomicAdd(&accF[d2 * 68 + 2 * lane],     bflo(w2));
        atomicAdd(&accF[d2 * 68 + 2 * lane + 1], bfhi(w2));
        atomicAdd(&accF[d3 * 68 + 2 * lane],     bflo(w3));
        atomicAdd(&accF[d3 * 68 + 2 * lane + 1], bfhi(w3));
        if (lane == 0) {
            atomicAdd(&sdeg[d0], 1); atomicAdd(&sdeg[d1], 1);
            atomicAdd(&sdeg[d2], 1); atomicAdd(&sdeg[d3], 1);
        }
    }
    for (; j < count; j += 16) {
        unsigned e = pp[j];
        unsigned w = u16b[(size_t)(e & 0x1FFFFu) * 32 + lane];
        int d = (e >> 17) & 127;
        atomicAdd(&accF[d * 68 + 2 * lane],     bflo(w));
        atomicAdd(&accF[d * 68 + 2 * lane + 1], bfhi(w));
        if (lane == 0) atomicAdd(&sdeg[d], 1);
    }
    __syncthreads();

    // ---- Phase H: h1 = relu(acc*invd + v), in LDS ----
    if (tid < 128) {
        int node = nodeBase + tid;
        float iv = (sdeg[tid] > 0) ? 1.0f / (float)sdeg[tid] : 1.0f;
        sInv[tid] = iv;
        if (node < N) invdArr[node] = iv;
    }
    __syncthreads();
    for (int i = tid * 4; i < 128 * 64; i += 2048) {
        int nl = i >> 6, k = i & 63;
        int node = nodeBase + nl;
        float4 vv = (node < N) ? *(const float4*)&v[(size_t)node * 64 + k]
                               : make_float4(0.f, 0.f, 0.f, 0.f);
        float4 a = *(float4*)&accF[nl * 68 + k];
        float iv = sInv[nl];
        a.x = fmaxf(a.x * iv + vv.x, 0.0f);
        a.y = fmaxf(a.y * iv + vv.y, 0.0f);
        a.z = fmaxf(a.z * iv + vv.z, 0.0f);
        a.w = fmaxf(a.w * iv + vv.w, 0.0f);
        *(float4*)&accF[nl * 68 + k] = a;
    }
    __syncthreads();

    // ---- Phase B: 128x64 GEMM from LDS (4 rows x 4 cols per thread) ----
    int mg = tid >> 4, ng = tid & 15;
    int m0 = mg * 4, n0 = ng * 4;

    float acc[4][4];
    #pragma unroll
    for (int mi = 0; mi < 4; ++mi)
        #pragma unroll
        for (int ni = 0; ni < 4; ++ni) acc[mi][ni] = 0.0f;

    #pragma unroll
    for (int k0 = 0; k0 < 64; k0 += 4) {
        float4 a[4], w[4];
        #pragma unroll
        for (int mi = 0; mi < 4; ++mi)
            a[mi] = *(float4*)&accF[(m0 + mi) * 68 + k0];
        #pragma unroll
        for (int kk = 0; kk < 4; ++kk)
            w[kk] = *(float4*)&sW[(k0 + kk) * 64 + n0];
        #pragma unroll
        for (int mi = 0; mi < 4; ++mi) {
            float am[4] = {a[mi].x, a[mi].y, a[mi].z, a[mi].w};
            #pragma unroll
            for (int kk = 0; kk < 4; ++kk) {
                acc[mi][0] = fmaf(am[kk], w[kk].x, acc[mi][0]);
                acc[mi][1] = fmaf(am[kk], w[kk].y, acc[mi][1]);
                acc[mi][2] = fmaf(am[kk], w[kk].z, acc[mi][2]);
                acc[mi][3] = fmaf(am[kk], w[kk].w, acc[mi][3]);
            }
        }
    }

    if (n0 < 32) {
        #pragma unroll
        for (int mi = 0; mi < 4; ++mi) {
            int node = nodeBase + m0 + mi;
            if (node >= N) continue;
            uint2 pk;
            pk.x = pack2(acc[mi][0], acc[mi][1]);
            pk.y = pack2(acc[mi][2], acc[mi][3]);
            *(uint2*)&P16b[(size_t)node * 16 + (n0 >> 1)] = pk;
        }
    } else {
        float4 b0 = *(const float4*)&b2[n0 - 32];
        #pragma unroll
        for (int mi = 0; mi < 4; ++mi) {
            int node = nodeBase + m0 + mi;
            if (node >= N) continue;
            *(float4*)&Qout[(size_t)node * 32 + (n0 - 32)] =
                make_float4(acc[mi][0]+b0.x, acc[mi][1]+b0.y,
                            acc[mi][2]+b0.z, acc[mi][3]+b0.w);
        }
    }
}

// --- A2: edge-parallel agg2 + trust head, one block per 128-node bucket -----
// 16-lane group per edge: acc2[local_dst] += P16b[src] (64B/edge).
__global__ __launch_bounds__(512) void k_a2(
    const unsigned* __restrict__ pairs, const int* __restrict__ gcnt,
    const unsigned* __restrict__ P16b, const float* __restrict__ Q,
    const float* __restrict__ invdArr,
    const float* __restrict__ Wt1, const float* __restrict__ bt1,
    const float* __restrict__ Wt2, const float* __restrict__ bt2,
    float* __restrict__ out_h, float* __restrict__ out_trust, int N)
{
    __shared__ float acc2[128 * 35];   // 17920B, stride 35 (bank-spread)
    __shared__ float sWt1[32 * 16];
    __shared__ float sWt2[16];
    __shared__ float sbt1[16];
    __shared__ float sInv[128];
    int tid = threadIdx.x;
    int b = blockIdx.x;
    int nodeBase = b * 128;

    for (int i = tid; i < 128 * 35; i += 512) acc2[i] = 0.0f;
    for (int i = tid; i < 512; i += 512) sWt1[i] = Wt1[i];
    if (tid < 16) { sWt2[tid] = Wt2[tid]; sbt1[tid] = bt1[tid]; }
    if (tid < 128) {
        int node = nodeBase + tid;
        sInv[tid] = (node < N) ? invdArr[node] : 1.0f;
    }
    __syncthreads();

    int count = min(gcnt[b], BCAP);
    const unsigned* pp = pairs + (size_t)b * BCAP;
    int grp = tid >> 4, lane = tid & 15;   // 32 groups of 16

    int j = grp;
    for (; j + 96 < count; j += 128) {
        unsigned e0 = pp[j], e1 = pp[j + 32], e2 = pp[j + 64], e3 = pp[j + 96];
        unsigned w0 = P16b[(size_t)(e0 & 0x1FFFFu) * 16 + lane];
        unsigned w1 = P16b[(size_t)(e1 & 0x1FFFFu) * 16 + lane];
        unsigned w2 = P16b[(size_t)(e2 & 0x1FFFFu) * 16 + lane];
        unsigned w3 = P16b[(size_t)(e3 & 0x1FFFFu) * 16 + lane];
        int d0 = (e0 >> 17) & 127, d1 = (e1 >> 17) & 127;
        int d2 = (e2 >> 17) & 127, d3 = (e3 >> 17) & 127;
        atomicAdd(&acc2[d0 * 35 + 2 * lane],     bflo(w0));
        atomicAdd(&acc2[d0 * 35 + 2 * lane + 1], bfhi(w0));
        atomicAdd(&acc2[d1 * 35 + 2 * lane],     bflo(w1));
        atomicAdd(&acc2[d1 * 35 + 2 * lane + 1], bfhi(w1));
        atomicAdd(&acc2[d2 * 35 + 2 * lane],     bflo(w2));
        atomicAdd(&acc2[d2 * 35 + 2 * lane + 1], bfhi(w2));
        atomicAdd(&acc2[d3 * 35 + 2 * lane],     bflo(w3));
        atomicAdd(&acc2[d3 * 35 + 2 * lane + 1], bfhi(w3));
    }
    for (; j < count; j += 32) {
        unsigned e = pp[j];
        unsigned w = P16b[(size_t)(e & 0x1FFFFu) * 16 + lane];
        int d = (e >> 17) & 127;
        atomicAdd(&acc2[d * 35 + 2 * lane],     bflo(w));
        atomicAdd(&acc2[d * 35 + 2 * lane + 1], bfhi(w));
    }
    __syncthreads();

    // ---- epilogue: h = acc*invd + Q -> out_h ; trust head ----
    #pragma unroll
    for (int r = 0; r < 4; ++r) {
        int nl = grp * 4 + r;
        int node = nodeBase + nl;
        if (node >= N) continue;
        float iv = sInv[nl];
        float2 qv = ((const float2*)Q)[(size_t)node * 16 + lane];
        float hx = acc2[nl * 35 + 2 * lane]     * iv + qv.x;
        float hy = acc2[nl * 35 + 2 * lane + 1] * iv + qv.y;
        ((float2*)out_h)[(size_t)node * 16 + lane] = make_float2(hx, hy);

        float t = sbt1[lane];
        #pragma unroll
        for (int k = 0; k < 16; ++k) {
            float hlo = __shfl(hx, k, 16);
            float hhi = __shfl(hy, k, 16);
            t += hlo * sWt1[(2 * k) * 16 + lane] + hhi * sWt1[(2 * k + 1) * 16 + lane];
        }
        t = fmaxf(t, 0.0f);
        float z = t * sWt2[lane];
        z += __shfl_xor(z, 1);
        z += __shfl_xor(z, 2);
        z += __shfl_xor(z, 4);
        z += __shfl_xor(z, 8);
        if (lane == 0) out_trust[node] = 1.0f / (1.0f + expf(-(z + bt2[0])));
    }
}

// ---------------------------------------------------------------------------

extern "C" void kernel_launch(void* const* d_in, const int* in_sizes, int n_in,
                              void* d_out, int out_size, void* d_ws, size_t ws_size,
                              hipStream_t stream)
{
    const float* x   = (const float*)d_in[0];
    const int*   ei  = (const int*)d_in[1];
    const float* Wl1 = (const float*)d_in[2];
    const float* Wr1 = (const float*)d_in[3];
    const float* b1  = (const float*)d_in[4];
    const float* Wl2 = (const float*)d_in[5];
    const float* Wr2 = (const float*)d_in[6];
    const float* b2  = (const float*)d_in[7];
    const float* Wt1 = (const float*)d_in[8];
    const float* bt1 = (const float*)d_in[9];
    const float* Wt2 = (const float*)d_in[10];
    const float* bt2 = (const float*)d_in[11];

    const int N = in_sizes[0] / 64;   // 100000
    const int E = in_sizes[1] / 2;    // 1600000
    const int* src = ei;
    const int* dst = ei + E;

    // Workspace layout (all segments 64B-aligned)
    unsigned* pairs  = (unsigned*)d_ws;                        // NBUCK*BCAP (~8.8MB)
    unsigned* u16b   = pairs + (size_t)NBUCK * BCAP;           // N*32 (bf16 x2)
    float*    v      = (float*)(u16b + (size_t)N * 32);        // N*64
    unsigned* P16b   = (unsigned*)(v + (size_t)N * 64);        // N*16 (bf16 x2)
    float*    Q      = (float*)(P16b + (size_t)N * 16);        // N*32
    float*    invdA  = Q + (size_t)N * 32;                     // N
    int*      gcnt   = (int*)(invdA + N);                      // 1024 (782 used)
    // total ~67 MB

    hipMemsetAsync(gcnt, 0, 1024 * sizeof(int), stream);

    const int GB  = (N + 63) / 64;               // 1563 gemm1 tiles
    const int BKB = (E + BKCHUNK - 1) / BKCHUNK; // 391 bucket chunks
    int grp = (GB + 3) / 4 > BKB ? (GB + 3) / 4 : BKB;   // 391
    k_m1<<<5 * grp, 256, 0, stream>>>(x, Wl1, Wr1, b1, u16b, v,
                                      src, dst, gcnt, pairs, N, E, GB, BKB);
    k_a1<<<NBUCK, 512, 0, stream>>>(pairs, gcnt, u16b, v, Wl2, Wr2, b2,
                                    P16b, Q, invdA, N);

    float* out_h     = (float*)d_out;
    float* out_trust = out_h + (size_t)N * 32;
    k_a2<<<NBUCK, 512, 0, stream>>>(pairs, gcnt, P16b, Q, invdA,
                                    Wt1, bt1, Wt2, bt2, out_h, out_trust, N);
}

// Round 10
// 307.884 us; speedup vs baseline: 3.9922x; 3.9922x over previous
//
#include <hip/hip_runtime.h>
#include <math.h>

// ---------------------------------------------------------------------------
// CommunityTrustGNN: 2-layer GraphSAGE (mean agg) + trust MLP head
// N=100000 nodes, E=1600000 edges, dims 64 -> 64 -> 32 -> (16 -> 1)
//
// Round 10: revert to round-8 gather structure (round 9's LDS-f32-atomic
// edge-parallel scheme was 10x slower: ds_add_f32 RMW serialization).
//  * k_csr DELETED: buckets are 64 dst-nodes; m2/a2 blocks rebuild their
//    bucket's CSR in LDS (64-bin histogram + 1-wave scan + LDS-cursor fill,
//    ~1K int LDS atomics/block). adj never touches global.
//  * m1 bucket chunks 4K->16K edges: per-bucket pairs-write bursts 21B->42B
//    (cuts the 47MB write amplification from round 7).
//  * Phase-A gather: proven register serial walk, unroll 8, adj from LDS.
// ---------------------------------------------------------------------------

#define NBUCK   1563     // ceil(100000/64) buckets of 64 dst nodes
#define BCAP    1536     // bucket capacity (mean 1024, +16 sigma)
#define BKCHUNK 16384    // edges per bucket-chunk block in M1

// bf16 helpers (round-to-nearest-even pack, exact unpack)
__device__ inline unsigned short f2bf(float x) {
    unsigned u = __float_as_uint(x);
    unsigned r = u + 0x7fffu + ((u >> 16) & 1u);
    return (unsigned short)(r >> 16);
}
__device__ inline unsigned pack2(float a, float b) {
    return (unsigned)f2bf(a) | ((unsigned)f2bf(b) << 16);
}
__device__ inline float bflo(unsigned u) { return __uint_as_float(u << 16); }
__device__ inline float bfhi(unsigned u) { return __uint_as_float(u & 0xffff0000u); }

// --- M1: interleaved gemm1 tiles + bucket-scatter chunks --------------------
// blockIdx%17==16 -> bucket chunk (blockIdx/17); else tile 16*(b/17)+(b%17).
// gemm1: u(bf16) = x@Wl1 ; v(f32) = x@Wr1 + b1  (two 64-col passes)
// bucket: edges -> packed (src | local_dst<<17), grouped by dst>>6
__global__ __launch_bounds__(256) void k_m1(
    const float* __restrict__ x,
    const float* __restrict__ Wl1, const float* __restrict__ Wr1,
    const float* __restrict__ b1,
    unsigned* __restrict__ u16b, float* __restrict__ v,
    const int* __restrict__ src, const int* __restrict__ dst,
    int* __restrict__ gcnt, unsigned* __restrict__ pairs,
    int N, int E, int GB, int BKB)
{
    __shared__ __align__(16) char smem[33792]; // sX 17408 + sW 16384 | hist 6252
    int tid = threadIdx.x;
    int g = blockIdx.x / 17, r17 = blockIdx.x % 17;

    if (r17 == 16) {
        // ---------------- bucket-scatter path ----------------
        if (g >= BKB) return;
        int* hist = (int*)smem;               // NBUCK ints
        int e0 = g * BKCHUNK;
        int e1 = min(e0 + BKCHUNK, E);

        for (int i = tid; i < NBUCK; i += 256) hist[i] = 0;
        __syncthreads();
        for (int e = e0 + tid; e < e1; e += 256)
            atomicAdd(&hist[((unsigned)dst[e]) >> 6], 1);
        __syncthreads();
        for (int i = tid; i < NBUCK; i += 256)
            if (hist[i] > 0)
                hist[i] = i * BCAP + atomicAdd(&gcnt[i], hist[i]);
        __syncthreads();
        for (int e = e0 + tid; e < e1; e += 256) {
            int t = dst[e];
            int b = ((unsigned)t) >> 6;
            int pos = atomicAdd(&hist[b], 1);
            if (pos < (b + 1) * BCAP)   // overflow clamp (16-sigma margin)
                pairs[pos] = (unsigned)src[e] | ((unsigned)(t & 63) << 17);
        }
        return;
    }

    // ---------------- gemm1 path ----------------
    int tile = 16 * g + r17;
    if (tile >= GB) return;
    float* sX = (float*)smem;             // 64 x stride68, row-major [m][k]
    float* sW = (float*)(smem + 17408);   // 64*64 [k][n], per pass
    int nblk = tile * 64;

    for (int i = tid * 4; i < 64 * 64; i += 1024) {
        int r = i >> 6, c = i & 63;
        int node = nblk + r;
        float4 xv = (node < N) ? *(const float4*)&x[(size_t)node * 64 + c]
                               : make_float4(0.f, 0.f, 0.f, 0.f);
        *(float4*)&sX[r * 68 + c] = xv;   // conflict-free b128 store
    }

    int mg = tid >> 4, ng = tid & 15;
    int m0 = mg * 4, n0 = ng * 4;

    #pragma unroll
    for (int pass = 0; pass < 2; ++pass) {
        const float* W = pass ? Wr1 : Wl1;
        if (pass) __syncthreads();
        for (int i = tid * 4; i < 64 * 64; i += 1024)
            *(float4*)&sW[i] = *(const float4*)&W[i];
        __syncthreads();

        float acc[4][4];
        #pragma unroll
        for (int mi = 0; mi < 4; ++mi)
            #pragma unroll
            for (int ni = 0; ni < 4; ++ni) acc[mi][ni] = 0.0f;

        #pragma unroll
        for (int k0 = 0; k0 < 64; k0 += 4) {
            float4 a[4], w[4];
            #pragma unroll
            for (int mi = 0; mi < 4; ++mi)
                a[mi] = *(float4*)&sX[(m0 + mi) * 68 + k0];
            #pragma unroll
            for (int kk = 0; kk < 4; ++kk)
                w[kk] = *(float4*)&sW[(k0 + kk) * 64 + n0];
            #pragma unroll
            for (int mi = 0; mi < 4; ++mi) {
                float am[4] = {a[mi].x, a[mi].y, a[mi].z, a[mi].w};
                #pragma unroll
                for (int kk = 0; kk < 4; ++kk) {
                    acc[mi][0] = fmaf(am[kk], w[kk].x, acc[mi][0]);
                    acc[mi][1] = fmaf(am[kk], w[kk].y, acc[mi][1]);
                    acc[mi][2] = fmaf(am[kk], w[kk].z, acc[mi][2]);
                    acc[mi][3] = fmaf(am[kk], w[kk].w, acc[mi][3]);
                }
            }
        }

        if (pass == 0) {
            #pragma unroll
            for (int mi = 0; mi < 4; ++mi) {
                int node = nblk + m0 + mi;
                if (node >= N) continue;
                uint2 pk;
                pk.x = pack2(acc[mi][0], acc[mi][1]);
                pk.y = pack2(acc[mi][2], acc[mi][3]);
                *(uint2*)&u16b[(size_t)node * 32 + (n0 >> 1)] = pk;
            }
        } else {
            float4 b0 = *(const float4*)&b1[n0];
            #pragma unroll
            for (int mi = 0; mi < 4; ++mi) {
                int node = nblk + m0 + mi;
                if (node >= N) continue;
                *(float4*)&v[(size_t)node * 64 + n0] =
                    make_float4(acc[mi][0]+b0.x, acc[mi][1]+b0.y,
                                acc[mi][2]+b0.z, acc[mi][3]+b0.w);
            }
        }
    }
}

// --- M2: local-CSR + agg1 + gemm2. Block = one 64-node bucket, 512 thr. -----
// CSR build in LDS, phase A register serial-walk gather (unroll 8),
// phase B 64x64 GEMM: P(bf16,32)=h1@Wl2 ; Q(f32,32)=h1@Wr2+b2.
__global__ __launch_bounds__(512) void k_m2(
    const unsigned* __restrict__ pairs, const int* __restrict__ gcnt,
    const unsigned* __restrict__ u16b, const float* __restrict__ v,
    const float* __restrict__ Wl2, const float* __restrict__ Wr2,
    const float* __restrict__ b2,
    unsigned* __restrict__ P16b, float* __restrict__ Qout, int N)
{
    __shared__ float sH[64 * 66];    // 16896B h1 tile, stride 66
    __shared__ float sW[64 * 64];    // 16384B: 0..31 Wl2 | 32..63 Wr2
    __shared__ int   sAdj[BCAP];     // 6144B
    __shared__ int   sOff[65];
    __shared__ int   sCur[64];
    int tid = threadIdx.x;
    int b = blockIdx.x;
    int nodeBase = b * 64;
    int count = min(gcnt[b], BCAP);
    const unsigned* pp = pairs + (size_t)b * BCAP;

    for (int i = tid * 4; i < 64 * 64; i += 2048) {
        int k = i >> 6, n = i & 63;
        const float* Wsrc = (n < 32) ? (Wl2 + k * 32 + n) : (Wr2 + k * 32 + (n - 32));
        *(float4*)&sW[k * 64 + n] = *(const float4*)Wsrc;
    }
    if (tid < 64) sCur[tid] = 0;
    __syncthreads();

    // ---- local CSR: histogram -> scan -> fill ----
    for (int j = tid; j < count; j += 512)
        atomicAdd(&sCur[(pp[j] >> 17) & 63], 1);
    __syncthreads();
    if (tid < 64) {
        int c = sCur[tid];
        int incl = c;
        #pragma unroll
        for (int off = 1; off < 64; off <<= 1) {
            int t = __shfl_up(incl, off);
            if (tid >= off) incl += t;
        }
        sOff[tid] = incl - c;
        if (tid == 63) sOff[64] = incl;
    }
    __syncthreads();
    if (tid < 64) sCur[tid] = sOff[tid];
    __syncthreads();
    for (int j = tid; j < count; j += 512) {
        unsigned e = pp[j];
        int pos = atomicAdd(&sCur[(e >> 17) & 63], 1);
        sAdj[pos] = (int)(e & 0x1FFFFu);
    }
    __syncthreads();

    // ---- Phase A: 16 half-waves x 4 nodes, register serial walk ----
    int hw = tid >> 5, lane = tid & 31;
    for (int r = 0; r < 4; ++r) {
        int nl = hw * 4 + r;
        int node = nodeBase + nl;
        float h0 = 0.0f, h1v = 0.0f;
        if (node < N) {
            int beg = sOff[nl], end = sOff[nl + 1];
            float lo[8] = {0,0,0,0,0,0,0,0}, hi[8] = {0,0,0,0,0,0,0,0};
            int i = beg;
            for (; i + 8 <= end; i += 8) {
                int s[8];
                #pragma unroll
                for (int j = 0; j < 8; ++j) s[j] = sAdj[i + j];
                #pragma unroll
                for (int j = 0; j < 8; ++j) {
                    unsigned w = u16b[(size_t)s[j] * 32 + lane];
                    lo[j] += bflo(w); hi[j] += bfhi(w);
                }
            }
            for (; i < end; ++i) {
                unsigned w = u16b[(size_t)sAdj[i] * 32 + lane];
                lo[0] += bflo(w); hi[0] += bfhi(w);
            }
            float mlo = ((lo[0]+lo[1])+(lo[2]+lo[3])) + ((lo[4]+lo[5])+(lo[6]+lo[7]));
            float mhi = ((hi[0]+hi[1])+(hi[2]+hi[3])) + ((hi[4]+hi[5])+(hi[6]+hi[7]));
            int deg = end - beg;
            float invd = (deg > 0) ? 1.0f / (float)deg : 1.0f;
            float2 vv = ((const float2*)v)[(size_t)node * 32 + lane];
            h0  = fmaxf(mlo * invd + vv.x, 0.0f);
            h1v = fmaxf(mhi * invd + vv.y, 0.0f);
        }
        *(float2*)&sH[nl * 66 + 2 * lane] = make_float2(h0, h1v);
    }
    __syncthreads();

    // ---- Phase B: 64x64 GEMM from LDS (2 rows x 4 cols per thread) ----
    int ng = tid & 15;
    int mg = tid >> 4;          // 0..31
    int m0 = mg * 2, n0 = ng * 4;

    float acc[2][4];
    #pragma unroll
    for (int mi = 0; mi < 2; ++mi)
        #pragma unroll
        for (int ni = 0; ni < 4; ++ni) acc[mi][ni] = 0.0f;

    #pragma unroll 8
    for (int k = 0; k < 64; ++k) {
        float a0 = sH[(m0 + 0) * 66 + k];
        float a1 = sH[(m0 + 1) * 66 + k];
        float4 w = *(float4*)&sW[k * 64 + n0];
        float wv[4] = {w.x, w.y, w.z, w.w};
        #pragma unroll
        for (int ni = 0; ni < 4; ++ni) {
            acc[0][ni] = fmaf(a0, wv[ni], acc[0][ni]);
            acc[1][ni] = fmaf(a1, wv[ni], acc[1][ni]);
        }
    }

    if (n0 < 32) {
        #pragma unroll
        for (int mi = 0; mi < 2; ++mi) {
            int node = nodeBase + m0 + mi;
            if (node >= N) continue;
            uint2 pk;
            pk.x = pack2(acc[mi][0], acc[mi][1]);
            pk.y = pack2(acc[mi][2], acc[mi][3]);
            *(uint2*)&P16b[(size_t)node * 16 + (n0 >> 1)] = pk;
        }
    } else {
        float4 b0 = *(const float4*)&b2[n0 - 32];
        #pragma unroll
        for (int mi = 0; mi < 2; ++mi) {
            int node = nodeBase + m0 + mi;
            if (node >= N) continue;
            *(float4*)&Qout[(size_t)node * 32 + (n0 - 32)] =
                make_float4(acc[mi][0]+b0.x, acc[mi][1]+b0.y,
                            acc[mi][2]+b0.z, acc[mi][3]+b0.w);
        }
    }
}

// --- A2: local-CSR + agg2 + trust. Block = one 64-node bucket, 256 thr. -----
// 16-lane group per node (4 nodes each); 64B coalesced edge gather, unroll 8.
__global__ __launch_bounds__(256) void k_a2(
    const unsigned* __restrict__ pairs, const int* __restrict__ gcnt,
    const unsigned* __restrict__ P16b, const float* __restrict__ Q,
    const float* __restrict__ Wt1, const float* __restrict__ bt1,
    const float* __restrict__ Wt2, const float* __restrict__ bt2,
    float* __restrict__ out_h, float* __restrict__ out_trust, int N)
{
    __shared__ int   sAdj[BCAP];
    __shared__ int   sOff[65];
    __shared__ int   sCur[64];
    __shared__ float sWt1[32 * 16];
    __shared__ float sWt2[16];
    __shared__ float sbt1[16];
    int tid = threadIdx.x;
    int b = blockIdx.x;
    int nodeBase = b * 64;
    int count = min(gcnt[b], BCAP);
    const unsigned* pp = pairs + (size_t)b * BCAP;

    for (int i = tid; i < 512; i += 256) sWt1[i] = Wt1[i];
    if (tid < 16) { sWt2[tid] = Wt2[tid]; sbt1[tid] = bt1[tid]; }
    if (tid < 64) sCur[tid] = 0;
    __syncthreads();

    for (int j = tid; j < count; j += 256)
        atomicAdd(&sCur[(pp[j] >> 17) & 63], 1);
    __syncthreads();
    if (tid < 64) {
        int c = sCur[tid];
        int incl = c;
        #pragma unroll
        for (int off = 1; off < 64; off <<= 1) {
            int t = __shfl_up(incl, off);
            if (tid >= off) incl += t;
        }
        sOff[tid] = incl - c;
        if (tid == 63) sOff[64] = incl;
    }
    __syncthreads();
    if (tid < 64) sCur[tid] = sOff[tid];
    __syncthreads();
    for (int j = tid; j < count; j += 256) {
        unsigned e = pp[j];
        int pos = atomicAdd(&sCur[(e >> 17) & 63], 1);
        sAdj[pos] = (int)(e & 0x1FFFFu);
    }
    __syncthreads();

    int grp = tid >> 4, lane = tid & 15;   // 16 groups of 16 lanes
    for (int r = 0; r < 4; ++r) {
        int nl = grp * 4 + r;
        int node = nodeBase + nl;
        if (node >= N) continue;
        int beg = sOff[nl], end = sOff[nl + 1];
        float lo[8] = {0,0,0,0,0,0,0,0}, hi[8] = {0,0,0,0,0,0,0,0};
        int i = beg;
        for (; i + 8 <= end; i += 8) {
            int s[8];
            #pragma unroll
            for (int j = 0; j < 8; ++j) s[j] = sAdj[i + j];
            #pragma unroll
            for (int j = 0; j < 8; ++j) {
                unsigned w = P16b[(size_t)s[j] * 16 + lane];
                lo[j] += bflo(w); hi[j] += bfhi(w);
            }
        }
        for (; i < end; ++i) {
            unsigned w = P16b[(size_t)sAdj[i] * 16 + lane];
            lo[0] += bflo(w); hi[0] += bfhi(w);
        }
        int deg = end - beg;
        float invd = (deg > 0) ? 1.0f / (float)deg : 1.0f;
        float mlo = (((lo[0]+lo[1])+(lo[2]+lo[3])) + ((lo[4]+lo[5])+(lo[6]+lo[7]))) * invd;
        float mhi = (((hi[0]+hi[1])+(hi[2]+hi[3])) + ((hi[4]+hi[5])+(hi[6]+hi[7]))) * invd;

        float2 qv = ((const float2*)Q)[(size_t)node * 16 + lane];
        float hx = mlo + qv.x;
        float hy = mhi + qv.y;
        ((float2*)out_h)[(size_t)node * 16 + lane] = make_float2(hx, hy);

        float t = sbt1[lane];
        #pragma unroll
        for (int k = 0; k < 16; ++k) {
            float hlo = __shfl(hx, k, 16);
            float hhi = __shfl(hy, k, 16);
            t += hlo * sWt1[(2 * k) * 16 + lane] + hhi * sWt1[(2 * k + 1) * 16 + lane];
        }
        t = fmaxf(t, 0.0f);
        float z = t * sWt2[lane];
        z += __shfl_xor(z, 1);
        z += __shfl_xor(z, 2);
        z += __shfl_xor(z, 4);
        z += __shfl_xor(z, 8);
        if (lane == 0) out_trust[node] = 1.0f / (1.0f + expf(-(z + bt2[0])));
    }
}

// ---------------------------------------------------------------------------

extern "C" void kernel_launch(void* const* d_in, const int* in_sizes, int n_in,
                              void* d_out, int out_size, void* d_ws, size_t ws_size,
                              hipStream_t stream)
{
    const float* x   = (const float*)d_in[0];
    const int*   ei  = (const int*)d_in[1];
    const float* Wl1 = (const float*)d_in[2];
    const float* Wr1 = (const float*)d_in[3];
    const float* b1  = (const float*)d_in[4];
    const float* Wl2 = (const float*)d_in[5];
    const float* Wr2 = (const float*)d_in[6];
    const float* b2  = (const float*)d_in[7];
    const float* Wt1 = (const float*)d_in[8];
    const float* bt1 = (const float*)d_in[9];
    const float* Wt2 = (const float*)d_in[10];
    const float* bt2 = (const float*)d_in[11];

    const int N = in_sizes[0] / 64;   // 100000
    const int E = in_sizes[1] / 2;    // 1600000
    const int* src = ei;
    const int* dst = ei + E;

    // Workspace layout (all segments 64B-aligned)
    unsigned* pairs  = (unsigned*)d_ws;                        // NBUCK*BCAP (~9.6MB)
    unsigned* u16b   = pairs + (size_t)NBUCK * BCAP;           // N*32 (bf16 x2)
    float*    v      = (float*)(u16b + (size_t)N * 32);        // N*64
    unsigned* P16b   = (unsigned*)(v + (size_t)N * 64);        // N*16 (bf16 x2)
    float*    Q      = (float*)(P16b + (size_t)N * 16);        // N*32
    int*      gcnt   = (int*)(Q + (size_t)N * 32);             // 1600 (1563 used)
    // total ~62 MB

    hipMemsetAsync(gcnt, 0, 1600 * sizeof(int), stream);

    const int GB  = (N + 63) / 64;               // 1563 gemm1 tiles
    const int BKB = (E + BKCHUNK - 1) / BKCHUNK; // 98 bucket chunks
    int grp = (GB + 15) / 16 > BKB ? (GB + 15) / 16 : BKB;   // 98
    k_m1<<<17 * grp, 256, 0, stream>>>(x, Wl1, Wr1, b1, u16b, v,
                                       src, dst, gcnt, pairs, N, E, GB, BKB);
    k_m2<<<NBUCK, 512, 0, stream>>>(pairs, gcnt, u16b, v, Wl2, Wr2, b2,
                                    P16b, Q, N);

    float* out_h     = (float*)d_out;
    float* out_trust = out_h + (size_t)N * 32;
    k_a2<<<NBUCK, 256, 0, stream>>>(pairs, gcnt, P16b, Q,
                                    Wt1, bt1, Wt2, bt2, out_h, out_trust, N);
}

// Round 11
// 233.179 us; speedup vs baseline: 5.2712x; 1.3204x over previous
//
#include <hip/hip_runtime.h>
#include <math.h>

// ---------------------------------------------------------------------------
// CommunityTrustGNN: 2-layer GraphSAGE (mean agg) + trust MLP head
// N=100000 nodes, E=1600000 edges, dims 64 -> 64 -> 32 -> (16 -> 1)
//
// Round 11 = round-8 (best, 246.9us) with ONLY proven deltas:
//  * k_m1: round-8 code verbatim (VGPR-lean; round-10's k-strip rewrite hit
//    252 VGPRs -> 7% occupancy). Bucket granularity 64 dst-nodes (1563 bins).
//  * k_m2: builds its bucket's CSR in LDS (histogram+scan+fill) and PERSISTS
//    adj/nodeOff to global -> standalone k_csr deleted, CSR built once.
//  * k_a2: round-8 version verbatim (reads global adj/nodeOff, no rebuild).
// ---------------------------------------------------------------------------

#define NBUCK   1563     // ceil(100000/64) buckets of 64 dst nodes
#define BCAP    1536     // bucket capacity (mean 1024, +16 sigma)
#define BKCHUNK 4096     // edges per bucket-chunk block in M1

// bf16 helpers (round-to-nearest-even pack, exact unpack)
__device__ inline unsigned short f2bf(float x) {
    unsigned u = __float_as_uint(x);
    unsigned r = u + 0x7fffu + ((u >> 16) & 1u);
    return (unsigned short)(r >> 16);
}
__device__ inline unsigned pack2(float a, float b) {
    return (unsigned)f2bf(a) | ((unsigned)f2bf(b) << 16);
}
__device__ inline float bflo(unsigned u) { return __uint_as_float(u << 16); }
__device__ inline float bfhi(unsigned u) { return __uint_as_float(u & 0xffff0000u); }

// --- M1: interleaved gemm1 tiles + bucket-scatter chunks --------------------
// blockIdx%5==4 -> bucket chunk (blockIdx/5); else gemm tile 4*(b/5)+(b%5).
// gemm1: u(bf16) = x@Wl1 ; v(f32) = x@Wr1 + b1  (two 64-col passes)
// bucket: edges -> packed (src | local_dst<<17), grouped by dst>>6
__global__ __launch_bounds__(256) void k_m1(
    const float* __restrict__ x,
    const float* __restrict__ Wl1, const float* __restrict__ Wr1,
    const float* __restrict__ b1,
    unsigned* __restrict__ u16b, float* __restrict__ v,
    const int* __restrict__ src, const int* __restrict__ dst,
    int* __restrict__ gcnt, unsigned* __restrict__ pairs,
    int N, int E, int GB, int BKB)
{
    __shared__ __align__(16) char smem[33792]; // sXT 17408 + sW 16384 | hist 6252
    int tid = threadIdx.x;
    int g = blockIdx.x / 5, r5 = blockIdx.x % 5;

    if (r5 == 4) {
        // ---------------- bucket-scatter path ----------------
        if (g >= BKB) return;
        int* hist = (int*)smem;               // NBUCK ints
        int e0 = g * BKCHUNK;
        int e1 = min(e0 + BKCHUNK, E);

        for (int i = tid; i < NBUCK; i += 256) hist[i] = 0;
        __syncthreads();
        for (int e = e0 + tid; e < e1; e += 256)
            atomicAdd(&hist[((unsigned)dst[e]) >> 6], 1);
        __syncthreads();
        for (int i = tid; i < NBUCK; i += 256)
            if (hist[i] > 0)
                hist[i] = i * BCAP + atomicAdd(&gcnt[i], hist[i]);
        __syncthreads();
        for (int e = e0 + tid; e < e1; e += 256) {
            int t = dst[e];
            int b = ((unsigned)t) >> 6;
            int pos = atomicAdd(&hist[b], 1);
            if (pos < (b + 1) * BCAP)   // overflow clamp (16-sigma margin)
                pairs[pos] = (unsigned)src[e] | ((unsigned)(t & 63) << 17);
        }
        return;
    }

    // ---------------- gemm1 path (round-8 verbatim: VGPR-lean) -------------
    int tile = 4 * g + r5;
    if (tile >= GB) return;
    float* sXT = (float*)smem;            // 64*68 [k][m]
    float* sW  = (float*)(smem + 17408);  // 64*64 [k][n], per pass
    int nblk = tile * 64;

    for (int i = tid * 4; i < 64 * 64; i += 1024) {
        int r = i >> 6, c = i & 63;
        int node = nblk + r;
        float4 xv = (node < N) ? *(const float4*)&x[(size_t)node * 64 + c]
                               : make_float4(0.f, 0.f, 0.f, 0.f);
        sXT[(c + 0) * 68 + r] = xv.x;
        sXT[(c + 1) * 68 + r] = xv.y;
        sXT[(c + 2) * 68 + r] = xv.z;
        sXT[(c + 3) * 68 + r] = xv.w;
    }

    int mg = tid >> 4, ng = tid & 15;
    int m0 = mg * 4, n0 = ng * 4;

    #pragma unroll
    for (int pass = 0; pass < 2; ++pass) {
        const float* W = pass ? Wr1 : Wl1;
        if (pass) __syncthreads();   // pass-0 reads done before restage
        for (int i = tid * 4; i < 64 * 64; i += 1024)
            *(float4*)&sW[i] = *(const float4*)&W[i];
        __syncthreads();

        float acc[4][4];
        #pragma unroll
        for (int mi = 0; mi < 4; ++mi)
            #pragma unroll
            for (int ni = 0; ni < 4; ++ni) acc[mi][ni] = 0.0f;

        #pragma unroll 8
        for (int k = 0; k < 64; ++k) {
            float4 a = *(float4*)&sXT[k * 68 + m0];
            float4 w = *(float4*)&sW[k * 64 + n0];
            float av[4] = {a.x, a.y, a.z, a.w};
            float wv[4] = {w.x, w.y, w.z, w.w};
            #pragma unroll
            for (int mi = 0; mi < 4; ++mi)
                #pragma unroll
                for (int ni = 0; ni < 4; ++ni)
                    acc[mi][ni] = fmaf(av[mi], wv[ni], acc[mi][ni]);
        }

        if (pass == 0) {
            #pragma unroll
            for (int mi = 0; mi < 4; ++mi) {
                int node = nblk + m0 + mi;
                if (node >= N) continue;
                uint2 pk;
                pk.x = pack2(acc[mi][0], acc[mi][1]);
                pk.y = pack2(acc[mi][2], acc[mi][3]);
                *(uint2*)&u16b[(size_t)node * 32 + (n0 >> 1)] = pk;
            }
        } else {
            float4 b0 = *(const float4*)&b1[n0];
            #pragma unroll
            for (int mi = 0; mi < 4; ++mi) {
                int node = nblk + m0 + mi;
                if (node >= N) continue;
                *(float4*)&v[(size_t)node * 64 + n0] =
                    make_float4(acc[mi][0]+b0.x, acc[mi][1]+b0.y,
                                acc[mi][2]+b0.z, acc[mi][3]+b0.w);
            }
        }
    }
}

// --- M2: local-CSR (persisted) + agg1 + gemm2. Block = 64-node bucket. ------
// CSR: LDS histogram -> 1-wave scan -> LDS-cursor fill; adj+nodeOff -> global.
// Phase A: 16 half-waves x 4 nodes register serial-walk gather (unroll 8).
// Phase B: 64x64 GEMM: P(bf16,32)=h1@Wl2 ; Q(f32,32)=h1@Wr2+b2.
__global__ __launch_bounds__(512) void k_m2(
    const unsigned* __restrict__ pairs, const int* __restrict__ gcnt,
    const unsigned* __restrict__ u16b, const float* __restrict__ v,
    const float* __restrict__ Wl2, const float* __restrict__ Wr2,
    const float* __restrict__ b2,
    unsigned* __restrict__ P16b, float* __restrict__ Qout,
    int2* __restrict__ nodeOff, int* __restrict__ adjG, int N)
{
    __shared__ float sH[64 * 66];    // 16896B h1 tile, stride 66
    __shared__ float sW[64 * 64];    // 16384B: 0..31 Wl2 | 32..63 Wr2
    __shared__ int   sAdj[BCAP];     // 6144B
    __shared__ int   sOff[65];
    __shared__ int   sCur[64];
    int tid = threadIdx.x;
    int b = blockIdx.x;
    int nodeBase = b * 64;
    int base = b * BCAP;
    int count = min(gcnt[b], BCAP);
    const unsigned* pp = pairs + (size_t)b * BCAP;

    for (int i = tid * 4; i < 64 * 64; i += 2048) {
        int k = i >> 6, n = i & 63;
        const float* Wsrc = (n < 32) ? (Wl2 + k * 32 + n) : (Wr2 + k * 32 + (n - 32));
        *(float4*)&sW[k * 64 + n] = *(const float4*)Wsrc;
    }
    if (tid < 64) sCur[tid] = 0;
    __syncthreads();

    // ---- local CSR: histogram -> scan -> fill ----
    for (int j = tid; j < count; j += 512)
        atomicAdd(&sCur[(pp[j] >> 17) & 63], 1);
    __syncthreads();
    if (tid < 64) {
        int c = sCur[tid];
        int incl = c;
        #pragma unroll
        for (int off = 1; off < 64; off <<= 1) {
            int t = __shfl_up(incl, off);
            if (tid >= off) incl += t;
        }
        sOff[tid] = incl - c;
        if (tid == 63) sOff[64] = incl;
    }
    __syncthreads();
    if (tid < 64) {
        sCur[tid] = sOff[tid];
        int node = nodeBase + tid;
        if (node < N)
            nodeOff[node] = make_int2(base + sOff[tid], sOff[tid + 1] - sOff[tid]);
    }
    __syncthreads();
    for (int j = tid; j < count; j += 512) {
        unsigned e = pp[j];
        int pos = atomicAdd(&sCur[(e >> 17) & 63], 1);
        sAdj[pos] = (int)(e & 0x1FFFFu);
    }
    __syncthreads();
    // persist adj for k_a2 (coalesced burst)
    for (int j = tid; j < count; j += 512) adjG[base + j] = sAdj[j];

    // ---- Phase A: 16 half-waves x 4 nodes, register serial walk ----
    int hw = tid >> 5, lane = tid & 31;
    for (int r = 0; r < 4; ++r) {
        int nl = hw * 4 + r;
        int node = nodeBase + nl;
        float h0 = 0.0f, h1v = 0.0f;
        if (node < N) {
            int beg = sOff[nl], end = sOff[nl + 1];
            float lo[8] = {0,0,0,0,0,0,0,0}, hi[8] = {0,0,0,0,0,0,0,0};
            int i = beg;
            for (; i + 8 <= end; i += 8) {
                int s[8];
                #pragma unroll
                for (int j = 0; j < 8; ++j) s[j] = sAdj[i + j];
                #pragma unroll
                for (int j = 0; j < 8; ++j) {
                    unsigned w = u16b[(size_t)s[j] * 32 + lane];
                    lo[j] += bflo(w); hi[j] += bfhi(w);
                }
            }
            for (; i < end; ++i) {
                unsigned w = u16b[(size_t)sAdj[i] * 32 + lane];
                lo[0] += bflo(w); hi[0] += bfhi(w);
            }
            float mlo = ((lo[0]+lo[1])+(lo[2]+lo[3])) + ((lo[4]+lo[5])+(lo[6]+lo[7]));
            float mhi = ((hi[0]+hi[1])+(hi[2]+hi[3])) + ((hi[4]+hi[5])+(hi[6]+hi[7]));
            int deg = end - beg;
            float invd = (deg > 0) ? 1.0f / (float)deg : 1.0f;
            float2 vv = ((const float2*)v)[(size_t)node * 32 + lane];
            h0  = fmaxf(mlo * invd + vv.x, 0.0f);
            h1v = fmaxf(mhi * invd + vv.y, 0.0f);
        }
        *(float2*)&sH[nl * 66 + 2 * lane] = make_float2(h0, h1v);
    }
    __syncthreads();

    // ---- Phase B: 64x64 GEMM from LDS (2 rows x 4 cols per thread) ----
    int ng = tid & 15;
    int mg = tid >> 4;          // 0..31
    int m0 = mg * 2, n0 = ng * 4;

    float acc[2][4];
    #pragma unroll
    for (int mi = 0; mi < 2; ++mi)
        #pragma unroll
        for (int ni = 0; ni < 4; ++ni) acc[mi][ni] = 0.0f;

    #pragma unroll 8
    for (int k = 0; k < 64; ++k) {
        float a0 = sH[(m0 + 0) * 66 + k];
        float a1 = sH[(m0 + 1) * 66 + k];
        float4 w = *(float4*)&sW[k * 64 + n0];
        float wv[4] = {w.x, w.y, w.z, w.w};
        #pragma unroll
        for (int ni = 0; ni < 4; ++ni) {
            acc[0][ni] = fmaf(a0, wv[ni], acc[0][ni]);
            acc[1][ni] = fmaf(a1, wv[ni], acc[1][ni]);
        }
    }

    if (n0 < 32) {
        #pragma unroll
        for (int mi = 0; mi < 2; ++mi) {
            int node = nodeBase + m0 + mi;
            if (node >= N) continue;
            uint2 pk;
            pk.x = pack2(acc[mi][0], acc[mi][1]);
            pk.y = pack2(acc[mi][2], acc[mi][3]);
            *(uint2*)&P16b[(size_t)node * 16 + (n0 >> 1)] = pk;
        }
    } else {
        float4 b0 = *(const float4*)&b2[n0 - 32];
        #pragma unroll
        for (int mi = 0; mi < 2; ++mi) {
            int node = nodeBase + m0 + mi;
            if (node >= N) continue;
            *(float4*)&Qout[(size_t)node * 32 + (n0 - 32)] =
                make_float4(acc[mi][0]+b0.x, acc[mi][1]+b0.y,
                            acc[mi][2]+b0.z, acc[mi][3]+b0.w);
        }
    }
}

// --- A2 (round-8 verbatim): h = mean(P[neigh]) + Q -> out_h ; trust head ----
// 16 lanes per node; 64B fully-coalesced edge gather, 8-deep MLP.
__global__ __launch_bounds__(256) void k_a2(
    const int2* __restrict__ nodeOff, const int* __restrict__ adj,
    const unsigned* __restrict__ P16b, const float* __restrict__ Q,
    const float* __restrict__ Wt1, const float* __restrict__ bt1,
    const float* __restrict__ Wt2, const float* __restrict__ bt2,
    float* __restrict__ out_h, float* __restrict__ out_trust, int N)
{
    __shared__ float sWt1[32 * 16];
    __shared__ float sWt2[16];
    for (int i = threadIdx.x; i < 512; i += 256) sWt1[i] = Wt1[i];
    if (threadIdx.x < 16) sWt2[threadIdx.x] = Wt2[threadIdx.x];
    __syncthreads();

    int n = blockIdx.x * 16 + (threadIdx.x >> 4);
    int lane = threadIdx.x & 15;
    if (n >= N) return;

    int2 od = nodeOff[n];
    int beg = od.x, end = od.x + od.y;
    float lo[8] = {0,0,0,0,0,0,0,0}, hi[8] = {0,0,0,0,0,0,0,0};
    int i = beg;
    for (; i + 8 <= end; i += 8) {
        int s[8];
        #pragma unroll
        for (int j = 0; j < 8; ++j) s[j] = adj[i + j];
        #pragma unroll
        for (int j = 0; j < 8; ++j) {
            unsigned w = P16b[(size_t)s[j] * 16 + lane];
            lo[j] += bflo(w); hi[j] += bfhi(w);
        }
    }
    for (; i < end; ++i) {
        unsigned w = P16b[(size_t)adj[i] * 16 + lane];
        lo[0] += bflo(w); hi[0] += bfhi(w);
    }
    float invd = (od.y > 0) ? 1.0f / (float)od.y : 1.0f;
    float mlo = (((lo[0]+lo[1])+(lo[2]+lo[3])) + ((lo[4]+lo[5])+(lo[6]+lo[7]))) * invd;
    float mhi = (((hi[0]+hi[1])+(hi[2]+hi[3])) + ((hi[4]+hi[5])+(hi[6]+hi[7]))) * invd;

    float2 qv = ((const float2*)Q)[(size_t)n * 16 + lane];
    float hx = mlo + qv.x;
    float hy = mhi + qv.y;

    ((float2*)out_h)[(size_t)n * 16 + lane] = make_float2(hx, hy);

    float t = bt1[lane];
    #pragma unroll
    for (int k = 0; k < 16; ++k) {
        float hlo = __shfl(hx, k, 16);
        float hhi = __shfl(hy, k, 16);
        t += hlo * sWt1[(2 * k) * 16 + lane] + hhi * sWt1[(2 * k + 1) * 16 + lane];
    }
    t = fmaxf(t, 0.0f);
    float z = t * sWt2[lane];
    z += __shfl_xor(z, 1);
    z += __shfl_xor(z, 2);
    z += __shfl_xor(z, 4);
    z += __shfl_xor(z, 8);
    if (lane == 0) out_trust[n] = 1.0f / (1.0f + expf(-(z + bt2[0])));
}

// ---------------------------------------------------------------------------

extern "C" void kernel_launch(void* const* d_in, const int* in_sizes, int n_in,
                              void* d_out, int out_size, void* d_ws, size_t ws_size,
                              hipStream_t stream)
{
    const float* x   = (const float*)d_in[0];
    const int*   ei  = (const int*)d_in[1];
    const float* Wl1 = (const float*)d_in[2];
    const float* Wr1 = (const float*)d_in[3];
    const float* b1  = (const float*)d_in[4];
    const float* Wl2 = (const float*)d_in[5];
    const float* Wr2 = (const float*)d_in[6];
    const float* b2  = (const float*)d_in[7];
    const float* Wt1 = (const float*)d_in[8];
    const float* bt1 = (const float*)d_in[9];
    const float* Wt2 = (const float*)d_in[10];
    const float* bt2 = (const float*)d_in[11];

    const int N = in_sizes[0] / 64;   // 100000
    const int E = in_sizes[1] / 2;    // 1600000
    const int* src = ei;
    const int* dst = ei + E;

    // Workspace layout (all segments 64B-aligned)
    unsigned* pairs  = (unsigned*)d_ws;                        // NBUCK*BCAP (~9.6MB)
    unsigned* u16b   = pairs + (size_t)NBUCK * BCAP;           // N*32 (bf16 x2)
    float*    v      = (float*)(u16b + (size_t)N * 32);        // N*64
    unsigned* P16b   = (unsigned*)(v + (size_t)N * 64);        // N*16 (bf16 x2)
    float*    Q      = (float*)(P16b + (size_t)N * 16);        // N*32
    int2*     nodeOff= (int2*)(Q + (size_t)N * 32);            // N
    int*      adj    = (int*)(nodeOff + N);                    // NBUCK*BCAP
    int*      gcnt   = adj + (size_t)NBUCK * BCAP;             // 2048 (1563 used)
    // total ~78 MB

    hipMemsetAsync(gcnt, 0, 2048 * sizeof(int), stream);

    const int GB  = (N + 63) / 64;               // 1563 gemm1 tiles
    const int BKB = (E + BKCHUNK - 1) / BKCHUNK; // 391 bucket chunks
    int grp = (GB + 3) / 4 > BKB ? (GB + 3) / 4 : BKB;   // 391
    k_m1<<<5 * grp, 256, 0, stream>>>(x, Wl1, Wr1, b1, u16b, v,
                                      src, dst, gcnt, pairs, N, E, GB, BKB);
    k_m2<<<NBUCK, 512, 0, stream>>>(pairs, gcnt, u16b, v, Wl2, Wr2, b2,
                                    P16b, Q, nodeOff, adj, N);

    float* out_h     = (float*)d_out;
    float* out_trust = out_h + (size_t)N * 32;
    k_a2<<<(N + 15) / 16, 256, 0, stream>>>(nodeOff, adj, P16b, Q,
                                            Wt1, bt1, Wt2, bt2,
                                            out_h, out_trust, N);
}